// Round 1
// baseline (1304.346 us; speedup 1.0000x reference)
//
#include <hip/hip_runtime.h>
#include <hip/hip_bf16.h>

// ModernNCA fused pipeline for MI355X (gfx950).
//
// Layout decisions:
//  - All MFMA via mfma_f32_16x16x32_f16 (f32 accum). Verified layouts:
//      A frag: A[m=lane&15][k=(lane>>4)*8 + j]  (16B contiguous row read)
//      B frag: B^T[n=lane&15][k=(lane>>4)*8 + j] (same pattern from [N][K])
//      C/D:    col=lane&15, row=(lane>>4)*4 + reg
//  - Candidates padded per-chunk: 5000 -> 5120 (20 chunks, N'=102400) so
//    64/256-wide tiles never cross a chunk boundary. Pad rows: c=0, csq=1e4
//    -> dist>=100 -> ed==0; each pad adds exp(0)=1 to sumexp, subtracted in
//    finalize (constant 120 per chunk).

typedef _Float16 f16x8 __attribute__((ext_vector_type(8)));
typedef float f32x4 __attribute__((ext_vector_type(4)));

#define MFMA16(a, b, c) __builtin_amdgcn_mfma_f32_16x16x32_f16(a, b, c, 0, 0, 0)

#define NPAD 102400     // 20 * 5120
#define DIM 512

// ---------------- prep: W1t/W2t transpose+cast, padded y, zero accumulators
// idx ranges: [0,49152) W1t | [49152,311296) W2t | [311296,413696) ypad |
//             [413696,547840) zero floats (csq,qsq,sumexp,logits contiguous)
__global__ __launch_bounds__(256) void prep_kernel(
    const float* __restrict__ W1, const float* __restrict__ W2,
    const int* __restrict__ y, _Float16* __restrict__ w1t,
    _Float16* __restrict__ w2t, int* __restrict__ ypad,
    float* __restrict__ zero_base) {
  int idx = blockIdx.x * 256 + threadIdx.x;
  if (idx < 49152) {                       // W1 [96,512] -> W1t [512,96]
    int n = idx / 96, k = idx - n * 96;
    w1t[idx] = (_Float16)W1[k * 512 + n];
  } else if (idx < 311296) {               // W2 [512,512] -> W2t [512,512]
    int j = idx - 49152;
    int n = j / 512, k = j - n * 512;
    w2t[j] = (_Float16)W2[k * 512 + n];
  } else if (idx < 413696) {               // padded candidate_y
    int j = idx - 311296;
    int ch = j / 5120, pos = j - ch * 5120;
    ypad[j] = (pos < 5000) ? y[ch * 5000 + pos] : 0;
  } else if (idx < 547840) {
    zero_base[idx - 413696] = 0.0f;
  }
}

// ---------------- fused 2-layer encoder: enc = relu(x@W1+b1)@W2 + b2
// 32 rows / block, 256 threads (4 waves), wave w covers cols [128w,128w+128).
// LDS: x tile (f16, padded stride 104) + h tile (f16, padded stride 520).
template <int CHUNK_IN, int CHUNK_OUT>
__global__ __launch_bounds__(256) void encode_kernel(
    const float* __restrict__ xn, const float* __restrict__ xc,
    const _Float16* __restrict__ w1t, const float* __restrict__ b1,
    const _Float16* __restrict__ w2t, const float* __restrict__ b2,
    _Float16* __restrict__ out, float* __restrict__ outsq) {
  __shared__ _Float16 lds_x[32 * 104];   // 96 cols + 8 pad (bank decorrelate)
  __shared__ _Float16 lds_h[32 * 520];   // 512 cols + 8 pad

  const int t = threadIdx.x;
  const int R0 = blockIdx.x * 32;

  // stage x (concat xn|xc) -> f16 LDS; invalid (pad) rows -> 0
  for (int idx = t; idx < 32 * 96; idx += 256) {
    int r = idx / 96, cc = idx - r * 96;
    int pr = R0 + r;
    int ch = pr / CHUNK_OUT;
    int pos = pr - ch * CHUNK_OUT;
    float v = 0.0f;
    if (pos < CHUNK_IN) {
      int orig = ch * CHUNK_IN + pos;
      v = (cc < 64) ? xn[orig * 64 + cc] : xc[orig * 32 + (cc - 64)];
    }
    lds_x[r * 104 + cc] = (_Float16)v;
  }
  __syncthreads();

  const int w = t >> 6, l = t & 63;
  const int l15 = l & 15, quad = l >> 4;
  const int ncol0 = w * 128;

  f32x4 acc[2][8];
#pragma unroll
  for (int mi = 0; mi < 2; mi++)
#pragma unroll
    for (int ni = 0; ni < 8; ni++) acc[mi][ni] = (f32x4)(0.0f);

  // phase 1: h = x @ W1  (K=96)
#pragma unroll
  for (int kt = 0; kt < 3; kt++) {
    f16x8 a[2];
#pragma unroll
    for (int mi = 0; mi < 2; mi++)
      a[mi] = *(const f16x8*)&lds_x[(mi * 16 + l15) * 104 + kt * 32 + quad * 8];
#pragma unroll
    for (int ni = 0; ni < 8; ni++) {
      f16x8 b = *(const f16x8*)&w1t[(ncol0 + ni * 16 + l15) * 96 + kt * 32 + quad * 8];
#pragma unroll
      for (int mi = 0; mi < 2; mi++) acc[mi][ni] = MFMA16(a[mi], b, acc[mi][ni]);
    }
  }

  // epilogue 1: +b1, relu, store h to LDS (f16)
#pragma unroll
  for (int mi = 0; mi < 2; mi++)
#pragma unroll
    for (int ni = 0; ni < 8; ni++) {
      float bb = b1[ncol0 + ni * 16 + l15];
#pragma unroll
      for (int r = 0; r < 4; r++) {
        float h = acc[mi][ni][r] + bb;
        h = fmaxf(h, 0.0f);
        lds_h[(mi * 16 + quad * 4 + r) * 520 + ncol0 + ni * 16 + l15] = (_Float16)h;
      }
    }
  __syncthreads();

  // phase 2: enc = h @ W2  (K=512)
#pragma unroll
  for (int mi = 0; mi < 2; mi++)
#pragma unroll
    for (int ni = 0; ni < 8; ni++) acc[mi][ni] = (f32x4)(0.0f);

  for (int kt = 0; kt < 16; kt++) {
    f16x8 a[2];
#pragma unroll
    for (int mi = 0; mi < 2; mi++)
      a[mi] = *(const f16x8*)&lds_h[(mi * 16 + l15) * 520 + kt * 32 + quad * 8];
#pragma unroll
    for (int ni = 0; ni < 8; ni++) {
      f16x8 b = *(const f16x8*)&w2t[(ncol0 + ni * 16 + l15) * 512 + kt * 32 + quad * 8];
#pragma unroll
      for (int mi = 0; mi < 2; mi++) acc[mi][ni] = MFMA16(a[mi], b, acc[mi][ni]);
    }
  }

  // epilogue 2: +b2, store f16 enc, row sum-of-squares (pad rows: 0 / 1e4)
  float b2v[8];
#pragma unroll
  for (int ni = 0; ni < 8; ni++) b2v[ni] = b2[ncol0 + ni * 16 + l15];

#pragma unroll
  for (int mi = 0; mi < 2; mi++) {
#pragma unroll
    for (int r = 0; r < 4; r++) {
      int pr = R0 + mi * 16 + quad * 4 + r;
      int ch = pr / CHUNK_OUT;
      int pos = pr - ch * CHUNK_OUT;
      bool valid = pos < CHUNK_IN;
      float s = 0.0f;
#pragma unroll
      for (int ni = 0; ni < 8; ni++) {
        float cv = acc[mi][ni][r] + b2v[ni];
        _Float16 hv = valid ? (_Float16)cv : (_Float16)0.0f;
        out[pr * 512 + ncol0 + ni * 16 + l15] = hv;
        float cvr = (float)hv;                       // square the ROUNDED value
        s += valid ? cvr * cvr : 19.53125f;          // 1e4/512 per pad element
      }
      s += __shfl_xor(s, 1);
      s += __shfl_xor(s, 2);
      s += __shfl_xor(s, 4);
      s += __shfl_xor(s, 8);
      if (l15 == 0) atomicAdd(&outsq[pr], s);        // 4 adds/row (one per wave)
    }
  }
}

// ---------------- fused distance + reductions
// grid (400, 16): bx = 256-col tile (never crosses a 5120 chunk), by = 64 rows.
// 4 waves, wave w -> rows m0=by*64+w*16 .. +16. Fragments loaded straight from
// global (q is L2-resident, c is L3-resident).
__global__ __launch_bounds__(256) void dist_kernel(
    const _Float16* __restrict__ q, const _Float16* __restrict__ c,
    const float* __restrict__ qsq, const float* __restrict__ csq,
    const int* __restrict__ ypad, float* __restrict__ sumexp,
    float* __restrict__ logits) {
  __shared__ float lds_logit[64 * 10];
  const int t = threadIdx.x, w = t >> 6, l = t & 63;
  const int l15 = l & 15, quad = l >> 4;
  const int bx = blockIdx.x, by = blockIdx.y;

  for (int i = t; i < 640; i += 256) lds_logit[i] = 0.0f;
  __syncthreads();

  const int m0 = by * 64 + w * 16;
  const int chunk = bx / 20;  // 20 col-blocks per 5120 chunk

  float qs[4];
#pragma unroll
  for (int r = 0; r < 4; r++) qs[r] = qsq[m0 + quad * 4 + r];
  float sume[4] = {0.0f, 0.0f, 0.0f, 0.0f};

  const _Float16* qbase = q + (m0 + l15) * 512 + quad * 8;

  for (int ct = 0; ct < 4; ct++) {
    int j0 = bx * 256 + ct * 64;
    f32x4 acc[4];
#pragma unroll
    for (int nt = 0; nt < 4; nt++) acc[nt] = (f32x4)(0.0f);

    for (int kt = 0; kt < 16; kt++) {
      f16x8 a = *(const f16x8*)(qbase + kt * 32);
#pragma unroll
      for (int nt = 0; nt < 4; nt++) {
        f16x8 b = *(const f16x8*)&c[(j0 + nt * 16 + l15) * 512 + kt * 32 + quad * 8];
        acc[nt] = MFMA16(a, b, acc[nt]);
      }
    }

#pragma unroll
    for (int nt = 0; nt < 4; nt++) {
      int col = j0 + nt * 16 + l15;
      float cs = csq[col];
      int yv = ypad[col];
#pragma unroll
      for (int r = 0; r < 4; r++) {
        float sq = qs[r] + cs - 2.0f * acc[nt][r];
        float d = sqrtf(fmaxf(sq, 0.0f));
        float ed = __expf(-d);                 // pad cols: d>=100 -> ed==0
        sume[r] += __expf(ed);                 // pad contributes exactly 1.0
        atomicAdd(&lds_logit[(w * 16 + quad * 4 + r) * 10 + yv], ed);
      }
    }
  }

#pragma unroll
  for (int r = 0; r < 4; r++) {
    float v = sume[r];
    v += __shfl_xor(v, 1);
    v += __shfl_xor(v, 2);
    v += __shfl_xor(v, 4);
    v += __shfl_xor(v, 8);
    if (l15 == 0) atomicAdd(&sumexp[(m0 + quad * 4 + r) * 20 + chunk], v);
  }
  __syncthreads();
  for (int i = t; i < 640; i += 256)
    atomicAdd(&logits[by * 640 + i], lds_logit[i]);
}

// ---------------- finalize: out[i,k] = log(logits[i,k]) - sum_ch log(sumexp-120)
__global__ __launch_bounds__(256) void finalize_kernel(
    const float* __restrict__ logits, const float* __restrict__ sumexp,
    float* __restrict__ out) {
  int i = blockIdx.x * 256 + threadIdx.x;
  if (i >= 1024) return;
  float lse = 0.0f;
#pragma unroll
  for (int ch = 0; ch < 20; ch++) lse += logf(sumexp[i * 20 + ch] - 120.0f);
#pragma unroll
  for (int k = 0; k < 10; k++) out[i * 10 + k] = logf(logits[i * 10 + k]) - lse;
}

extern "C" void kernel_launch(void* const* d_in, const int* in_sizes, int n_in,
                              void* d_out, int out_size, void* d_ws, size_t ws_size,
                              hipStream_t stream) {
  const float* x_num = (const float*)d_in[0];
  const float* x_cat = (const float*)d_in[1];
  const float* cxn   = (const float*)d_in[2];
  const float* cxc   = (const float*)d_in[3];
  const int*   cy    = (const int*)d_in[4];
  const float* W1    = (const float*)d_in[5];
  const float* b1    = (const float*)d_in[6];
  const float* W2    = (const float*)d_in[7];
  const float* b2    = (const float*)d_in[8];
  float* out = (float*)d_out;

  char* ws = (char*)d_ws;
  // ws layout (bytes), all 1KB-aligned; total ~107.5 MB
  _Float16* c    = (_Float16*)(ws + 0);           // 102400*512*2 = 104857600
  _Float16* qe   = (_Float16*)(ws + 104857600);   // 1024*512*2   = 1048576
  _Float16* w1t  = (_Float16*)(ws + 105906176);   // 512*96*2     = 98304
  _Float16* w2t  = (_Float16*)(ws + 106004480);   // 512*512*2    = 524288
  float*    csq  = (float*)(ws + 106528768);      // 102400*4     = 409600
  float*    qsq  = (float*)(ws + 106938368);      // 1024*4       = 4096
  float*    sume = (float*)(ws + 106942464);      // 1024*20*4    = 81920
  float*    lgts = (float*)(ws + 107024384);      // 1024*10*4    = 40960
  int*      ypad = (int*)(ws + 107065344);        // 102400*4     = 409600

  prep_kernel<<<2140, 256, 0, stream>>>(W1, W2, cy, w1t, w2t, ypad, csq);
  // candidates: 100000 rows, chunk 5000 -> 5120 padded (3200 blocks of 32 rows)
  encode_kernel<5000, 5120><<<3200, 256, 0, stream>>>(cxn, cxc, w1t, b1, w2t, b2, c, csq);
  // queries: 1024 rows, no padding
  encode_kernel<(1 << 20), (1 << 20)><<<32, 256, 0, stream>>>(x_num, x_cat, w1t, b1, w2t, b2, qe, qsq);
  dist_kernel<<<dim3(400, 16), 256, 0, stream>>>(qe, c, qsq, csq, ypad, sume, lgts);
  finalize_kernel<<<4, 256, 0, stream>>>(lgts, sume, out);
}

// Round 2
// 1105.002 us; speedup vs baseline: 1.1804x; 1.1804x over previous
//
#include <hip/hip_runtime.h>
#include <hip/hip_bf16.h>

// ModernNCA fused pipeline for MI355X (gfx950). Round 2: latency-bound fix.
//
//  - dist: q a-frags persist in registers; c staged via global_load_lds(16B)
//    into XOR-swizzled LDS (swizzle on the GLOBAL address side, since the LDS
//    destination of global_load_lds is fixed wave-base + lane*16). Double
//    buffer, ONE barrier per K-block, prefetch issued after the barrier so the
//    compiler's vmcnt(0)-before-s_barrier waits exactly on the tile we are
//    about to read while the next tile loads during compute.
//  - encode: MFMA roles swapped (A=weight frags from global, B=x/h row frags
//    from swizzled LDS) so C-layout yields 4 consecutive output cols per lane
//    -> b64 LDS/global stores. w2t frags register-pipelined one kt ahead.
//  - Padding scheme unchanged: 5000->5120 per chunk; pad rows c=0, csq=1e4 ->
//    ed==0 exactly; each pad adds exp(0)=1 to sumexp, finalize subtracts 120.

typedef _Float16 f16x8 __attribute__((ext_vector_type(8)));
typedef _Float16 f16x4 __attribute__((ext_vector_type(4)));
typedef float f32x4 __attribute__((ext_vector_type(4)));

#define MFMA16(a, b, c) __builtin_amdgcn_mfma_f32_16x16x32_f16(a, b, c, 0, 0, 0)

#define GLL16(gp, lp)                                                          \
  __builtin_amdgcn_global_load_lds(                                            \
      (const __attribute__((address_space(1))) unsigned int*)(gp),             \
      (__attribute__((address_space(3))) unsigned int*)(lp), 16, 0, 0)

// ---------------- prep: W1t/W2t transpose+cast, padded y, zero accumulators
__global__ __launch_bounds__(256) void prep_kernel(
    const float* __restrict__ W1, const float* __restrict__ W2,
    const int* __restrict__ y, _Float16* __restrict__ w1t,
    _Float16* __restrict__ w2t, int* __restrict__ ypad,
    float* __restrict__ zero_base) {
  int idx = blockIdx.x * 256 + threadIdx.x;
  if (idx < 49152) {                       // W1 [96,512] -> W1t [512,96]
    int n = idx / 96, k = idx - n * 96;
    w1t[idx] = (_Float16)W1[k * 512 + n];
  } else if (idx < 311296) {               // W2 [512,512] -> W2t [512,512]
    int j = idx - 49152;
    int n = j / 512, k = j - n * 512;
    w2t[j] = (_Float16)W2[k * 512 + n];
  } else if (idx < 413696) {               // padded candidate_y
    int j = idx - 311296;
    int ch = j / 5120, pos = j - ch * 5120;
    ypad[j] = (pos < 5000) ? y[ch * 5000 + pos] : 0;
  } else if (idx < 547840) {
    zero_base[idx - 413696] = 0.0f;
  }
}

// ---------------- fused 2-layer encoder: enc = relu(x@W1+b1)@W2 + b2
template <int CHUNK_IN, int CHUNK_OUT>
__global__ __launch_bounds__(256) void encode_kernel(
    const float* __restrict__ xn, const float* __restrict__ xc,
    const _Float16* __restrict__ w1t, const float* __restrict__ b1,
    const _Float16* __restrict__ w2t, const float* __restrict__ b2,
    _Float16* __restrict__ out, float* __restrict__ outsq) {
  __shared__ __align__(16) char lds_x[8192];   // 32 rows x 16 units(16B) swizzled
  __shared__ __align__(16) char lds_h[32768];  // 32 rows x 64 units(16B) swizzled

  const int t = threadIdx.x;
  const int R0 = blockIdx.x * 32;
  const int w = t >> 6, l = t & 63;
  const int l15 = l & 15, quad = l >> 4;
  const int ncol0 = w * 128;

  // ---- stage x (f32 -> f16, swizzled): unit kq of row holds cols kq*8..+8
#pragma unroll
  for (int it = 0; it < 2; it++) {
    int idx = it * 256 + t;
    int row = idx >> 4, kq = idx & 15;
    int pr = R0 + row;
    int ch = pr / CHUNK_OUT, pos = pr - ch * CHUNK_OUT;
    float v[8] = {0, 0, 0, 0, 0, 0, 0, 0};
    if (pos < CHUNK_IN && kq < 12) {
      int orig = ch * CHUNK_IN + pos;
      float4 f0, f1;
      if (kq < 8) {
        f0 = *(const float4*)&xn[orig * 64 + kq * 8];
        f1 = *(const float4*)&xn[orig * 64 + kq * 8 + 4];
      } else {
        f0 = *(const float4*)&xc[orig * 32 + (kq - 8) * 8];
        f1 = *(const float4*)&xc[orig * 32 + (kq - 8) * 8 + 4];
      }
      v[0] = f0.x; v[1] = f0.y; v[2] = f0.z; v[3] = f0.w;
      v[4] = f1.x; v[5] = f1.y; v[6] = f1.z; v[7] = f1.w;
    }
    f16x8 hv;
#pragma unroll
    for (int j = 0; j < 8; j++) hv[j] = (_Float16)v[j];
    *(f16x8*)&lds_x[row * 256 + (((kq ^ (row & 7)) & 15) << 4)] = hv;
  }
  __syncthreads();

  // ---- phase 1: h = x @ W1  (K=96)
  f32x4 acc1[8][2];
#pragma unroll
  for (int ni = 0; ni < 8; ni++)
#pragma unroll
    for (int rt = 0; rt < 2; rt++) acc1[ni][rt] = (f32x4)(0.0f);

#pragma unroll
  for (int kt = 0; kt < 3; kt++) {
    f16x8 bx[2];
#pragma unroll
    for (int rt = 0; rt < 2; rt++) {
      int row = rt * 16 + l15;
      int kq = kt * 4 + quad;
      bx[rt] = *(const f16x8*)&lds_x[row * 256 + ((kq ^ (row & 7)) << 4)];
    }
#pragma unroll
    for (int ni = 0; ni < 8; ni++) {
      f16x8 aw = *(const f16x8*)&w1t[(ncol0 + ni * 16 + l15) * 96 + kt * 32 + quad * 8];
#pragma unroll
      for (int rt = 0; rt < 2; rt++) acc1[ni][rt] = MFMA16(aw, bx[rt], acc1[ni][rt]);
    }
  }

  // ---- epilogue 1: +b1, relu, b64 write to swizzled lds_h
#pragma unroll
  for (int ni = 0; ni < 8; ni++) {
    float4 b1v = *(const float4*)&b1[ncol0 + ni * 16 + quad * 4];
    int kq2 = (ncol0 >> 3) + ni * 2 + (quad >> 1);
#pragma unroll
    for (int rt = 0; rt < 2; rt++) {
      int row = rt * 16 + l15;
      f16x4 hv;
      hv[0] = (_Float16)fmaxf(acc1[ni][rt][0] + b1v.x, 0.0f);
      hv[1] = (_Float16)fmaxf(acc1[ni][rt][1] + b1v.y, 0.0f);
      hv[2] = (_Float16)fmaxf(acc1[ni][rt][2] + b1v.z, 0.0f);
      hv[3] = (_Float16)fmaxf(acc1[ni][rt][3] + b1v.w, 0.0f);
      int swz = (kq2 & ~7) | ((kq2 & 7) ^ (row & 7));
      *(f16x4*)&lds_h[row * 1024 + (swz << 4) + ((quad & 1) << 3)] = hv;
    }
  }
  __syncthreads();

  // ---- phase 2: enc = h @ W2  (K=512), w2t frags pipelined one kt ahead
  f32x4 acc2[8][2];
#pragma unroll
  for (int ni = 0; ni < 8; ni++)
#pragma unroll
    for (int rt = 0; rt < 2; rt++) acc2[ni][rt] = (f32x4)(0.0f);

  f16x8 awc[8], bhc[2];
#pragma unroll
  for (int ni = 0; ni < 8; ni++)
    awc[ni] = *(const f16x8*)&w2t[(ncol0 + ni * 16 + l15) * 512 + quad * 8];
#pragma unroll
  for (int rt = 0; rt < 2; rt++) {
    int row = rt * 16 + l15;
    int swz = (quad & ~7) | ((quad & 7) ^ (row & 7));
    bhc[rt] = *(const f16x8*)&lds_h[row * 1024 + (swz << 4)];
  }

  for (int kt = 0; kt < 16; kt++) {
    f16x8 awn[8], bhn[2];
    int ktn = (kt + 1) & 15;
#pragma unroll
    for (int ni = 0; ni < 8; ni++)
      awn[ni] = *(const f16x8*)&w2t[(ncol0 + ni * 16 + l15) * 512 + ktn * 32 + quad * 8];
#pragma unroll
    for (int rt = 0; rt < 2; rt++) {
      int row = rt * 16 + l15;
      int kq = ktn * 4 + quad;
      int swz = (kq & ~7) | ((kq & 7) ^ (row & 7));
      bhn[rt] = *(const f16x8*)&lds_h[row * 1024 + (swz << 4)];
    }
#pragma unroll
    for (int ni = 0; ni < 8; ni++)
#pragma unroll
      for (int rt = 0; rt < 2; rt++)
        acc2[ni][rt] = MFMA16(awc[ni], bhc[rt], acc2[ni][rt]);
#pragma unroll
    for (int ni = 0; ni < 8; ni++) awc[ni] = awn[ni];
    bhc[0] = bhn[0]; bhc[1] = bhn[1];
  }

  // ---- epilogue 2: +b2, b64 global store, row sum-of-squares
#pragma unroll
  for (int rt = 0; rt < 2; rt++) {
    int pr = R0 + rt * 16 + l15;
    int ch = pr / CHUNK_OUT, pos = pr - ch * CHUNK_OUT;
    bool valid = pos < CHUNK_IN;
    float s = 0.0f;
#pragma unroll
    for (int ni = 0; ni < 8; ni++) {
      float4 b2v = *(const float4*)&b2[ncol0 + ni * 16 + quad * 4];
      f16x4 ov;
      if (valid) {
        ov[0] = (_Float16)(acc2[ni][rt][0] + b2v.x);
        ov[1] = (_Float16)(acc2[ni][rt][1] + b2v.y);
        ov[2] = (_Float16)(acc2[ni][rt][2] + b2v.z);
        ov[3] = (_Float16)(acc2[ni][rt][3] + b2v.w);
#pragma unroll
        for (int r = 0; r < 4; r++) {
          float cv = (float)ov[r];
          s += cv * cv;
        }
      } else {
        ov[0] = (_Float16)0.0f; ov[1] = (_Float16)0.0f;
        ov[2] = (_Float16)0.0f; ov[3] = (_Float16)0.0f;
        s += 4.0f * 19.53125f;               // 1e4 / 512 per pad element
      }
      *(f16x4*)&out[pr * 512 + ncol0 + ni * 16 + quad * 4] = ov;
    }
    s += __shfl_xor(s, 16);
    s += __shfl_xor(s, 32);
    if (quad == 0) atomicAdd(&outsq[pr], s);  // 4 adds/row (one per wave)
  }
}

// ---------------- fused distance + reductions
// grid (16 by fast, 400 bx slow): blocks sharing a c-tile are dispatch-
// adjacent (L2 locality). Block: 64 q-rows x 256 c-cols, K=512.
__global__ __launch_bounds__(256) void dist_kernel(
    const _Float16* __restrict__ q, const _Float16* __restrict__ c,
    const float* __restrict__ qsq, const float* __restrict__ csq,
    const int* __restrict__ ypad, float* __restrict__ sumexp,
    float* __restrict__ logits) {
  __shared__ __align__(16) char lds_c[65536];  // 2 x (256 cols x 8 units(16B))
  __shared__ float lds_logit[640];

  const int t = threadIdx.x, w = t >> 6, l = t & 63;
  const int l15 = l & 15, quad = l >> 4;
  const int by = blockIdx.x, bx = blockIdx.y;
  const int m0 = by * 64 + w * 16;

  for (int i = t; i < 640; i += 256) lds_logit[i] = 0.0f;

  // preload q a-frags: rows m0+l15, full K (L2-resident, 16 independent loads)
  f16x8 a[16];
  const _Float16* qb = q + (m0 + l15) * 512 + quad * 8;
#pragma unroll
  for (int kt = 0; kt < 16; kt++) a[kt] = *(const f16x8*)(qb + kt * 32);

  const _Float16* cb = c + (size_t)bx * 256 * 512;

  // stage K-block 0 into buffer 0
#pragma unroll
  for (int i = 0; i < 8; i++) {
    int coll = i * 32 + (t >> 3);
    int kq = (t & 7) ^ (coll & 7);
    GLL16(cb + coll * 512 + kq * 8, lds_c + i * 4096 + w * 1024);
  }

  f32x4 acc[16];
#pragma unroll
  for (int ni = 0; ni < 16; ni++) acc[ni] = (f32x4)(0.0f);

#pragma unroll
  for (int kb = 0; kb < 8; kb++) {
    __syncthreads();  // vmcnt(0) drain: this kb's tile is now in LDS
    if (kb < 7) {     // async prefetch of next tile during compute
      const _Float16* cbn = cb + (kb + 1) * 64;
#pragma unroll
      for (int i = 0; i < 8; i++) {
        int coll = i * 32 + (t >> 3);
        int kq = (t & 7) ^ (coll & 7);
        GLL16(cbn + coll * 512 + kq * 8,
              lds_c + (((kb + 1) & 1) << 15) + i * 4096 + w * 1024);
      }
    }
    const char* cl = lds_c + ((kb & 1) << 15);
#pragma unroll
    for (int kt2 = 0; kt2 < 2; kt2++) {
      int kq = kt2 * 4 + quad;
#pragma unroll
      for (int ni = 0; ni < 16; ni++) {
        int coll = ni * 16 + l15;
        f16x8 b = *(const f16x8*)(cl + coll * 128 + ((kq ^ (coll & 7)) << 4));
        acc[ni] = MFMA16(a[kb * 2 + kt2], b, acc[ni]);
      }
    }
  }

  // epilogue: sqrt/exp, per-row chunk sumexp, one-hot logits
  float qs[4];
#pragma unroll
  for (int r = 0; r < 4; r++) qs[r] = qsq[m0 + quad * 4 + r];

  float sume[4] = {0.0f, 0.0f, 0.0f, 0.0f};
#pragma unroll
  for (int ni = 0; ni < 16; ni++) {
    int colg = bx * 256 + ni * 16 + l15;
    float cs = csq[colg];
    int yv = ypad[colg];
#pragma unroll
    for (int r = 0; r < 4; r++) {
      float sq = qs[r] + cs - 2.0f * acc[ni][r];
      float d = sqrtf(fmaxf(sq, 0.0f));
      float ed = __expf(-d);                 // pad cols: d>=100 -> ed==0
      sume[r] += __expf(ed);                 // pad contributes exactly 1.0
      atomicAdd(&lds_logit[(w * 16 + quad * 4 + r) * 10 + yv], ed);
    }
  }
  const int chunk = bx / 20;
#pragma unroll
  for (int r = 0; r < 4; r++) {
    float v = sume[r];
    v += __shfl_xor(v, 1);
    v += __shfl_xor(v, 2);
    v += __shfl_xor(v, 4);
    v += __shfl_xor(v, 8);
    if (l15 == 0) atomicAdd(&sumexp[(m0 + quad * 4 + r) * 20 + chunk], v);
  }
  __syncthreads();
  for (int i = t; i < 640; i += 256)
    atomicAdd(&logits[by * 640 + i], lds_logit[i]);
}

// ---------------- finalize: out[i,k] = log(logits[i,k]) - sum_ch log(sumexp-120)
__global__ __launch_bounds__(256) void finalize_kernel(
    const float* __restrict__ logits, const float* __restrict__ sumexp,
    float* __restrict__ out) {
  int i = blockIdx.x * 256 + threadIdx.x;
  if (i >= 1024) return;
  float lse = 0.0f;
#pragma unroll
  for (int ch = 0; ch < 20; ch++) lse += logf(sumexp[i * 20 + ch] - 120.0f);
#pragma unroll
  for (int k = 0; k < 10; k++) out[i * 10 + k] = logf(logits[i * 10 + k]) - lse;
}

extern "C" void kernel_launch(void* const* d_in, const int* in_sizes, int n_in,
                              void* d_out, int out_size, void* d_ws, size_t ws_size,
                              hipStream_t stream) {
  const float* x_num = (const float*)d_in[0];
  const float* x_cat = (const float*)d_in[1];
  const float* cxn   = (const float*)d_in[2];
  const float* cxc   = (const float*)d_in[3];
  const int*   cy    = (const int*)d_in[4];
  const float* W1    = (const float*)d_in[5];
  const float* b1    = (const float*)d_in[6];
  const float* W2    = (const float*)d_in[7];
  const float* b2    = (const float*)d_in[8];
  float* out = (float*)d_out;

  char* ws = (char*)d_ws;
  _Float16* c    = (_Float16*)(ws + 0);           // 102400*512*2 = 104857600
  _Float16* qe   = (_Float16*)(ws + 104857600);   // 1024*512*2   = 1048576
  _Float16* w1t  = (_Float16*)(ws + 105906176);   // 512*96*2     = 98304
  _Float16* w2t  = (_Float16*)(ws + 106004480);   // 512*512*2    = 524288
  float*    csq  = (float*)(ws + 106528768);      // 102400*4     = 409600
  float*    qsq  = (float*)(ws + 106938368);      // 1024*4       = 4096
  float*    sume = (float*)(ws + 106942464);      // 1024*20*4    = 81920
  float*    lgts = (float*)(ws + 107024384);      // 1024*10*4    = 40960
  int*      ypad = (int*)(ws + 107065344);        // 102400*4     = 409600

  prep_kernel<<<2140, 256, 0, stream>>>(W1, W2, cy, w1t, w2t, ypad, csq);
  encode_kernel<5000, 5120><<<3200, 256, 0, stream>>>(cxn, cxc, w1t, b1, w2t, b2, c, csq);
  encode_kernel<(1 << 20), (1 << 20)><<<32, 256, 0, stream>>>(x_num, x_cat, w1t, b1, w2t, b2, qe, qsq);
  dist_kernel<<<dim3(16, 400), 256, 0, stream>>>(qe, c, qsq, csq, ypad, sume, lgts);
  finalize_kernel<<<4, 256, 0, stream>>>(lgts, sume, out);
}